// Round 1
// baseline (2467.675 us; speedup 1.0000x reference)
//
#include <hip/hip_runtime.h>
#include <stdint.h>

typedef __attribute__((ext_vector_type(8))) short s16x8;
typedef __attribute__((ext_vector_type(4))) float f32x4;

static __device__ __forceinline__ unsigned short f2bf(float f) {
  unsigned u = __float_as_uint(f);
  u += 0x7FFFu + ((u >> 16) & 1u);
  return (unsigned short)(u >> 16);
}
static __device__ __forceinline__ float bf2f(unsigned short h) {
  return __uint_as_float(((unsigned)h) << 16);
}

// ---------------- weight prep ----------------
__global__ void k_wtct(const float* __restrict__ W, float* __restrict__ T) {
  int idx = blockIdx.x * 256 + threadIdx.x;        // 196608 = 768*256
  int k = idx >> 8, o = idx & 255;
  T[idx] = W[o * 768 + k];
}

__global__ void k_wc3(const float* __restrict__ W, unsigned short* __restrict__ T) {
  int idx = blockIdx.x * 256 + threadIdx.x;        // 1327104 = 27*192*256
  int tap = idx / 49152;
  int rem = idx - tap * 49152;
  int oc = rem >> 8, ic = rem & 255;
  T[idx] = f2bf(W[(oc * 256 + ic) * 27 + tap]);
}

// ---------------- restore + cam_x (output 2) ----------------
__global__ void k_restore(const float* __restrict__ cx, const int* __restrict__ ids,
                          const float* __restrict__ mtok, float* __restrict__ out) {
  int idx = blockIdx.x * 256 + threadIdx.x;        // 811008 = 6*768*176
  int p = idx % 176;
  int r = idx / 176;
  int ch = r % 768;
  int c = r / 768;
  int id = ids[c * 176 + p];
  out[idx] = (id < 44) ? cx[((size_t)(c * 44 + id)) * 768 + ch] : mtok[ch];
}

// ---------------- vf / feat: relu(camx @ W_tc^T + b) + embeds ----------------
__global__ __launch_bounds__(256) void k_vf(const float* __restrict__ camx, const float* __restrict__ WtT,
                                            const float* __restrict__ btc, const float* __restrict__ cemb,
                                            const float* __restrict__ lemb, float* __restrict__ feat) {
  __shared__ float sa[768];
  int blk = blockIdx.x;                            // c*176 + p
  int c = blk / 176, p = blk - c * 176;
  int t = threadIdx.x;
  for (int i = t; i < 768; i += 256) sa[i] = camx[((size_t)(c * 768 + i)) * 176 + p];
  __syncthreads();
  float acc = 0.f;
  for (int k = 0; k < 768; ++k) acc += sa[k] * WtT[k * 256 + t];
  feat[(size_t)blk * 256 + t] = fmaxf(acc + btc[t], 0.f) + cemb[c * 256 + t] + lemb[t];
}

// ---------------- generic bf16 MFMA GEMM ----------------
// C[M,N] = act(A[M,K] @ B[K,N] + bias).  A f32 row-major (lda), B f32 [K][N].
// tap >= 0: deconv mode: B read as deconv_w[o][i][tap] (o=col,i=k), output
// scattered bf16 into x1[(od*100+oh)*16+ow][256].
__global__ __launch_bounds__(256) void k_gemm(
    const float* __restrict__ A, int M, int lda,
    const float* __restrict__ B, int K, int N,
    const float* __restrict__ bias, int relu,
    float* __restrict__ Cf, int ldc,
    unsigned short* __restrict__ Cscat, int tap) {
  __shared__ short sA[128 * 40];
  __shared__ short sB[64 * 40];
  const int t = threadIdx.x;
  const int l = t & 63, w = t >> 6;
  const int row0 = blockIdx.x * 128, n0 = blockIdx.y * 64;
  f32x4 acc[2][4] = {};
  const int rowA = t >> 1, halfA = t & 1;

  for (int kc = 0; kc < K; kc += 32) {
    __syncthreads();
    {  // stage A (convert f32 -> bf16)
      union { unsigned short s[8]; uint4 v; } p0, p1;
      int r = row0 + rowA;
      if (r < M) {
        const float* src = A + (size_t)r * lda + kc + halfA * 16;
        float4 f0 = ((const float4*)src)[0];
        float4 f1 = ((const float4*)src)[1];
        float4 f2 = ((const float4*)src)[2];
        float4 f3 = ((const float4*)src)[3];
        p0.s[0] = f2bf(f0.x); p0.s[1] = f2bf(f0.y); p0.s[2] = f2bf(f0.z); p0.s[3] = f2bf(f0.w);
        p0.s[4] = f2bf(f1.x); p0.s[5] = f2bf(f1.y); p0.s[6] = f2bf(f1.z); p0.s[7] = f2bf(f1.w);
        p1.s[0] = f2bf(f2.x); p1.s[1] = f2bf(f2.y); p1.s[2] = f2bf(f2.z); p1.s[3] = f2bf(f2.w);
        p1.s[4] = f2bf(f3.x); p1.s[5] = f2bf(f3.y); p1.s[6] = f2bf(f3.z); p1.s[7] = f2bf(f3.w);
      } else {
        p0.v = make_uint4(0u, 0u, 0u, 0u);
        p1.v = make_uint4(0u, 0u, 0u, 0u);
      }
      *(uint4*)&sA[rowA * 40 + halfA * 16] = p0.v;
      *(uint4*)&sA[rowA * 40 + halfA * 16 + 8] = p1.v;
    }
#pragma unroll
    for (int i = 0; i < 8; ++i) {  // stage B: [col][k] layout
      int e = t + i * 256;         // 2048 = 32k * 64n
      int kk = e >> 6, nn = e & 63;
      int n = n0 + nn;
      float v = 0.f;
      if (n < N) {
        if (tap >= 0) v = B[((size_t)n * 256 + kc + kk) * 8 + tap];
        else v = B[(size_t)(kc + kk) * N + n];
      }
      sB[nn * 40 + kk] = (short)f2bf(v);
    }
    __syncthreads();
    s16x8 a0 = *(const s16x8*)&sA[(w * 32 + (l & 15)) * 40 + (l >> 4) * 8];
    s16x8 a1 = *(const s16x8*)&sA[(w * 32 + 16 + (l & 15)) * 40 + (l >> 4) * 8];
#pragma unroll
    for (int nb = 0; nb < 4; ++nb) {
      s16x8 b = *(const s16x8*)&sB[(nb * 16 + (l & 15)) * 40 + (l >> 4) * 8];
      acc[0][nb] = __builtin_amdgcn_mfma_f32_16x16x32_bf16(a0, b, acc[0][nb], 0, 0, 0);
      acc[1][nb] = __builtin_amdgcn_mfma_f32_16x16x32_bf16(a1, b, acc[1][nb], 0, 0, 0);
    }
  }
  // epilogue: C/D layout col = lane&15, row = (lane>>4)*4 + reg
#pragma unroll
  for (int m = 0; m < 2; ++m)
#pragma unroll
    for (int nb = 0; nb < 4; ++nb)
#pragma unroll
      for (int r = 0; r < 4; ++r) {
        int row = row0 + w * 32 + m * 16 + ((l >> 4) << 2) + r;
        int col = n0 + nb * 16 + (l & 15);
        if (row < M && col < N) {
          float v = acc[m][nb][r];
          if (bias) v += bias[col];
          if (relu) v = fmaxf(v, 0.f);
          if (tap >= 0) {
            int z = row / 2500, rr = row - z * 2500;
            int hy = rr / 50, wx = rr - hy * 50;
            int t1 = tap >> 2, t2 = (tap >> 1) & 1, t3 = tap & 1;
            int od = 2 * wx + 1 - t1, oh = 2 * hy + 1 - t2, ow = 2 * z + 1 - t3;
            Cscat[((size_t)((od * 100 + oh) * 16 + ow)) * 256 + col] = f2bf(v);
          } else {
            Cf[(size_t)row * ldc + col] = v;
          }
        }
      }
}

// ---------------- softmax + bilinear sampling + aggregate ----------------
__global__ __launch_bounds__(256) void k_sample(const float* __restrict__ off, const float* __restrict__ attl,
                                                const float* __restrict__ val, float* __restrict__ agg) {
  __shared__ float sl[96], sw[96];
  int n = blockIdx.x, t = threadIdx.x;
  if (t < 96) sl[t] = attl[(size_t)n * 96 + t];
  __syncthreads();
  if (t < 8) {
    float mx = -1e30f;
    for (int j = 0; j < 12; ++j) mx = fmaxf(mx, sl[t * 12 + j]);
    float s = 0.f;
    for (int j = 0; j < 12; ++j) s += __expf(sl[t * 12 + j] - mx);
    float inv = 1.f / s;
    for (int j = 0; j < 12; ++j) sw[t * 12 + j] = __expf(sl[t * 12 + j] - mx) * inv;
  }
  __syncthreads();
  int h = t >> 5, d = t & 31;
  float xr = ((float)(n % 50) + 0.5f) * (22.0f / 50.0f) - 0.5f;
  float yr = ((float)((n / 50) % 50) + 0.5f) * (8.0f / 50.0f) - 0.5f;
  float acc = 0.f;
  const float* offn = off + (size_t)n * 192 + h * 24;  // [h][c][p][2]
  const float* vbh = val + (size_t)h * 32 + d;
#pragma unroll
  for (int c = 0; c < 6; ++c)
#pragma unroll
    for (int p2 = 0; p2 < 2; ++p2) {
      float x = xr + offn[(c * 2 + p2) * 2];
      float y = yr + offn[(c * 2 + p2) * 2 + 1];
      float x0 = floorf(x), y0 = floorf(y);
      float wx = x - x0, wy = y - y0;
      int ix0 = min(max((int)x0, 0), 21), ix1 = min(max((int)x0 + 1, 0), 21);
      int iy0 = min(max((int)y0, 0), 7), iy1 = min(max((int)y0 + 1, 0), 7);
      const float* vb = vbh + (size_t)c * 176 * 256;
      float v00 = vb[(size_t)(iy0 * 22 + ix0) * 256];
      float v01 = vb[(size_t)(iy0 * 22 + ix1) * 256];
      float v10 = vb[(size_t)(iy1 * 22 + ix0) * 256];
      float v11 = vb[(size_t)(iy1 * 22 + ix1) * 256];
      float bil = (1.f - wx) * (1.f - wy) * v00 + wx * (1.f - wy) * v01 +
                  (1.f - wx) * wy * v10 + wx * wy * v11;
      acc += sw[h * 12 + c * 2 + p2] * bil;
    }
  agg[(size_t)n * 256 + t] = acc;
}

// ---------------- residual + LayerNorm(256), writes q in place ----------------
__global__ __launch_bounds__(256) void k_addln(float* __restrict__ q, const float* __restrict__ p,
                                               const float* __restrict__ g, const float* __restrict__ b) {
  __shared__ float s1[256], s2[256];
  int n = blockIdx.x, t = threadIdx.x;
  float x = q[(size_t)n * 256 + t] + p[(size_t)n * 256 + t];
  s1[t] = x; s2[t] = x * x;
  __syncthreads();
  for (int s = 128; s > 0; s >>= 1) {
    if (t < s) { s1[t] += s1[t + s]; s2[t] += s2[t + s]; }
    __syncthreads();
  }
  float mean = s1[0] * (1.0f / 256.0f);
  float var = s2[0] * (1.0f / 256.0f) - mean * mean;
  q[(size_t)n * 256 + t] = (x - mean) * rsqrtf(var + 1e-5f) * g[t] + b[t];
}

// ---------------- GroupNorm 1 (256 ch, 16 groups) over x1 [160000][256] bf16 ----------------
__global__ __launch_bounds__(256) void k_gnstat1(const unsigned short* __restrict__ X, float* __restrict__ part) {
  __shared__ float s1[256], s2[256];
  int b = blockIdx.x, t = threadIdx.x;   // 2500 blocks * 16384 elems
  unsigned base = (unsigned)b * 16384u + (unsigned)t;
  float a = 0.f, q = 0.f;
  for (int i = 0; i < 64; ++i) { float v = bf2f(X[base + (unsigned)i * 256u]); a += v; q += v * v; }
  s1[t] = a; s2[t] = q;
  __syncthreads();
  for (int s = 8; s > 0; s >>= 1) {
    if ((t & 15) < s) { s1[t] += s1[t + s]; s2[t] += s2[t + s]; }
    __syncthreads();
  }
  if ((t & 15) == 0) {
    part[(t >> 4) * 2500 + b] = s1[t];
    part[40000 + (t >> 4) * 2500 + b] = s2[t];
  }
}

__global__ __launch_bounds__(256) void k_gnred1(const float* __restrict__ part, float* __restrict__ gmv) {
  __shared__ float s1[256], s2[256];
  int g = blockIdx.x, t = threadIdx.x;   // 16 blocks
  float a = 0.f, q = 0.f;
  for (int i = t; i < 2500; i += 256) { a += part[g * 2500 + i]; q += part[40000 + g * 2500 + i]; }
  s1[t] = a; s2[t] = q;
  __syncthreads();
  for (int s = 128; s > 0; s >>= 1) {
    if (t < s) { s1[t] += s1[t + s]; s2[t] += s2[t + s]; }
    __syncthreads();
  }
  if (t == 0) {
    float m = s1[0] / 2560000.0f;
    float v = s2[0] / 2560000.0f - m * m;
    gmv[2 * g] = m; gmv[2 * g + 1] = rsqrtf(v + 1e-5f);
  }
}

__global__ __launch_bounds__(256) void k_gnapply1(unsigned short* __restrict__ X, const float* __restrict__ gmv,
                                                  const float* __restrict__ g, const float* __restrict__ b) {
  for (unsigned idx = blockIdx.x * 256 + threadIdx.x; idx < 40960000u; idx += gridDim.x * 256) {
    int oc = idx & 255, grp = oc >> 4;
    float v = bf2f(X[idx]);
    v = (v - gmv[grp * 2]) * gmv[grp * 2 + 1] * g[oc] + b[oc];
    X[idx] = f2bf(fmaxf(v, 0.f));
  }
}

// ---------------- conv3 3x3x3 (256->192) via tap-decomposed MFMA GEMM ----------------
// X: x1 normalized bf16 [vox=100*100*16][256]; Wp: [27][192][256] bf16; Y: [192][160000] bf16
__global__ __launch_bounds__(256) void k_conv3(const unsigned short* __restrict__ X,
                                               const unsigned short* __restrict__ Wp,
                                               unsigned short* __restrict__ Y) {
  __shared__ short sX[540 * 40];   // 3 od x 10 oh x 18 ow positions, 32 ic (pad 40)
  __shared__ short sW[192 * 40];   // 192 oc x 32 ic (pad 40)
  const int od = blockIdx.x;        // 0..99
  const int oh0 = blockIdx.y * 8;   // 0..96
  const int t = threadIdx.x;
  const int l = t & 63, w = t >> 6;
  f32x4 acc[2][12] = {};

  for (int chunk = 0; chunk < 8; ++chunk) {
    const int ic0 = chunk * 32;
    __syncthreads();
#pragma unroll
    for (int i = 0; i < 17; ++i) {  // stage slab: 540 pos * 8 uint2
      int e = t + i * 256;
      if (e < 4320) {
        int pos = e >> 3, jj = e & 7;
        int sd = pos / 180, r2 = pos - sd * 180;
        int sh = r2 / 18, sw_ = r2 - sh * 18;
        int gd = od + sd - 1, gh = oh0 + sh - 1, gw = sw_ - 1;
        uint2 v = make_uint2(0u, 0u);
        if ((unsigned)gd < 100u && (unsigned)gh < 100u && (unsigned)gw < 16u)
          v = *(const uint2*)&X[((size_t)((gd * 100 + gh) * 16 + gw)) * 256 + ic0 + jj * 4];
        *(uint2*)&sX[pos * 40 + jj * 4] = v;
      }
    }
    for (int tap = 0; tap < 27; ++tap) {
      __syncthreads();
#pragma unroll
      for (int i = 0; i < 6; ++i) {  // stage weights: 192 oc * 8 uint2
        int e = t + i * 256;
        int oc = e >> 3, jj = e & 7;
        uint2 v = *(const uint2*)&Wp[((size_t)tap * 192 + oc) * 256 + ic0 + jj * 4];
        *(uint2*)&sW[oc * 40 + jj * 4] = v;
      }
      __syncthreads();
      const int t1 = tap / 9, tr = tap - t1 * 9, t2 = tr / 3, t3 = tr - t2 * 3;
      s16x8 a[2];
#pragma unroll
      for (int m = 0; m < 2; ++m) {
        int vl = w * 32 + m * 16 + (l & 15);
        int ohl = vl >> 4, ow = vl & 15;
        int pos = (t1 * 10 + ohl + t2) * 18 + ow + t3;
        a[m] = *(const s16x8*)&sX[pos * 40 + (l >> 4) * 8];
      }
#pragma unroll
      for (int nb = 0; nb < 12; ++nb) {
        s16x8 b = *(const s16x8*)&sW[(nb * 16 + (l & 15)) * 40 + (l >> 4) * 8];
        acc[0][nb] = __builtin_amdgcn_mfma_f32_16x16x32_bf16(a[0], b, acc[0][nb], 0, 0, 0);
        acc[1][nb] = __builtin_amdgcn_mfma_f32_16x16x32_bf16(a[1], b, acc[1][nb], 0, 0, 0);
      }
    }
  }
#pragma unroll
  for (int m = 0; m < 2; ++m)
#pragma unroll
    for (int nb = 0; nb < 12; ++nb)
#pragma unroll
      for (int r = 0; r < 4; ++r) {
        int oc = nb * 16 + (l & 15);
        int vl = w * 32 + m * 16 + ((l >> 4) << 2) + r;
        int ohl = vl >> 4, ow = vl & 15;
        int oh = oh0 + ohl;
        if (oh < 100)
          Y[(size_t)oc * 160000 + (size_t)((od * 100 + oh) * 16) + ow] = f2bf(acc[m][nb][r]);
      }
}

// ---------------- GroupNorm 2 (192 ch, 16 groups) over [192][160000] bf16 ----------------
__global__ __launch_bounds__(256) void k_gnstat2(const unsigned short* __restrict__ X, float* __restrict__ part) {
  __shared__ float s1[256], s2[256];
  int b = blockIdx.x, t = threadIdx.x;   // 1920 blocks: ch = b/10, part p = b%10
  int ch = b / 10, pp = b - ch * 10;
  unsigned base = (unsigned)ch * 160000u + (unsigned)pp * 16000u;
  float a = 0.f, q = 0.f;
  for (int i = t; i < 16000; i += 256) { float v = bf2f(X[base + i]); a += v; q += v * v; }
  s1[t] = a; s2[t] = q;
  __syncthreads();
  for (int s = 128; s > 0; s >>= 1) {
    if (t < s) { s1[t] += s1[t + s]; s2[t] += s2[t + s]; }
    __syncthreads();
  }
  if (t == 0) { part[80000 + ch * 10 + pp] = s1[0]; part[81920 + ch * 10 + pp] = s2[0]; }
}

__global__ __launch_bounds__(256) void k_gnred2(const float* __restrict__ part, float* __restrict__ gmv) {
  __shared__ float s1[256], s2[256];
  int g = blockIdx.x, t = threadIdx.x;   // 16 blocks, 120 partials each (12 ch * 10)
  float a = (t < 120) ? part[80000 + g * 120 + t] : 0.f;
  float q = (t < 120) ? part[81920 + g * 120 + t] : 0.f;
  s1[t] = a; s2[t] = q;
  __syncthreads();
  for (int s = 128; s > 0; s >>= 1) {
    if (t < s) { s1[t] += s1[t + s]; s2[t] += s2[t + s]; }
    __syncthreads();
  }
  if (t == 0) {
    float m = s1[0] / 1920000.0f;
    float v = s2[0] / 1920000.0f - m * m;
    gmv[2 * g] = m; gmv[2 * g + 1] = rsqrtf(v + 1e-5f);
  }
}

__global__ __launch_bounds__(256) void k_gnapply2(const unsigned short* __restrict__ X, const float* __restrict__ gmv,
                                                  const float* __restrict__ g, const float* __restrict__ b,
                                                  float* __restrict__ out) {
  for (unsigned idx = blockIdx.x * 256 + threadIdx.x; idx < 30720000u; idx += gridDim.x * 256) {
    unsigned oc = idx / 160000u;
    unsigned grp = oc / 12u;
    float v = bf2f(X[idx]);
    v = (v - gmv[grp * 2]) * gmv[grp * 2 + 1] * g[oc] + b[oc];
    out[idx] = fmaxf(v, 0.f);
  }
}

// ---------------- host ----------------
static inline dim3 gemm_grid(int M, int N) { return dim3((M + 127) / 128, (N + 63) / 64); }

extern "C" void kernel_launch(void* const* d_in, const int* in_sizes, int n_in,
                              void* d_out, int out_size, void* d_ws, size_t ws_size,
                              hipStream_t stream) {
  const float* camera_x = (const float*)d_in[0];
  const int* ids = (const int*)d_in[1];
  const float* mask_tok = (const float*)d_in[4];
  const float* vol_emb = (const float*)d_in[5];
  const float* W_tc = (const float*)d_in[6];
  const float* b_tc = (const float*)d_in[7];
  const float* cams_emb = (const float*)d_in[8];
  const float* lvl_emb = (const float*)d_in[9];
  const float* W_off = (const float*)d_in[10];
  const float* b_off = (const float*)d_in[11];
  const float* W_att = (const float*)d_in[12];
  const float* b_att = (const float*)d_in[13];
  const float* W_val = (const float*)d_in[14];
  const float* b_val = (const float*)d_in[15];
  const float* W_out = (const float*)d_in[16];
  const float* b_out = (const float*)d_in[17];
  const float* ln1_g = (const float*)d_in[18];
  const float* ln1_b = (const float*)d_in[19];
  const float* W_ff1 = (const float*)d_in[20];
  const float* b_ff1 = (const float*)d_in[21];
  const float* W_ff2 = (const float*)d_in[22];
  const float* b_ff2 = (const float*)d_in[23];
  const float* ln2_g = (const float*)d_in[24];
  const float* ln2_b = (const float*)d_in[25];
  const float* deconv_w = (const float*)d_in[26];
  const float* gn1_g = (const float*)d_in[27];
  const float* gn1_b = (const float*)d_in[28];
  const float* conv3_w = (const float*)d_in[29];
  const float* gn2_g = (const float*)d_in[30];
  const float* gn2_b = (const float*)d_in[31];

  char* ws = (char*)d_ws;
  float* q = (float*)(ws + 0);
  float* feat = (float*)(ws + 81920000);
  float* val = (float*)(ws + 83001344);
  float* offb = (float*)(ws + 84082688);
  float* attl = (float*)(ws + 84082688 + 15360000);
  float* agg = (float*)(ws + 84082688 + 23040000);
  float* proj = (float*)(ws + 84082688 + 43520000);
  float* ffh = (float*)(ws + 84082688 + 64000000);
  unsigned short* x1bf = (unsigned short*)(ws + 84082688);  // aliases decoder scratch (dead)
  unsigned short* c3 = (unsigned short*)(ws + 0);           // aliases q (dead after deconv)
  float* wtcT = (float*)(ws + 189042688);
  unsigned short* wc3 = (unsigned short*)(ws + 189829120);
  float* part = (float*)(ws + 192483328);
  float* gmv1 = (float*)(ws + 192818688);
  float* gmv2 = (float*)(ws + 192818816);

  float* out_x = (float*)d_out;
  float* out_camx = out_x + 30720000;

  k_wtct<<<768, 256, 0, stream>>>(W_tc, wtcT);
  k_wc3<<<5184, 256, 0, stream>>>(conv3_w, wc3);
  k_restore<<<3168, 256, 0, stream>>>(camera_x, ids, mask_tok, out_camx);
  k_vf<<<1056, 256, 0, stream>>>(out_camx, wtcT, b_tc, cams_emb, lvl_emb, feat);
  hipMemcpyAsync(q, vol_emb, (size_t)20000 * 256 * 4, hipMemcpyDeviceToDevice, stream);

  for (int lyr = 0; lyr < 3; ++lyr) {
    k_gemm<<<gemm_grid(1056, 256), 256, 0, stream>>>(feat, 1056, 256, W_val + lyr * 65536, 256, 256,
                                                     b_val + lyr * 256, 0, val, 256, nullptr, -1);
    k_gemm<<<gemm_grid(20000, 192), 256, 0, stream>>>(q, 20000, 256, W_off + lyr * 49152, 256, 192,
                                                      b_off + lyr * 192, 0, offb, 192, nullptr, -1);
    k_gemm<<<gemm_grid(20000, 96), 256, 0, stream>>>(q, 20000, 256, W_att + lyr * 24576, 256, 96,
                                                     b_att + lyr * 96, 0, attl, 96, nullptr, -1);
    k_sample<<<20000, 256, 0, stream>>>(offb, attl, val, agg);
    k_gemm<<<gemm_grid(20000, 256), 256, 0, stream>>>(agg, 20000, 256, W_out + lyr * 65536, 256, 256,
                                                      b_out + lyr * 256, 0, proj, 256, nullptr, -1);
    k_addln<<<20000, 256, 0, stream>>>(q, proj, ln1_g + lyr * 256, ln1_b + lyr * 256);
    k_gemm<<<gemm_grid(20000, 512), 256, 0, stream>>>(q, 20000, 256, W_ff1 + lyr * 131072, 256, 512,
                                                      b_ff1 + lyr * 512, 1, ffh, 512, nullptr, -1);
    k_gemm<<<gemm_grid(20000, 256), 256, 0, stream>>>(ffh, 20000, 512, W_ff2 + lyr * 131072, 512, 256,
                                                      b_ff2 + lyr * 256, 0, proj, 256, nullptr, -1);
    k_addln<<<20000, 256, 0, stream>>>(q, proj, ln2_g + lyr * 256, ln2_b + lyr * 256);
  }

  for (int tap = 0; tap < 8; ++tap)
    k_gemm<<<gemm_grid(20000, 256), 256, 0, stream>>>(q, 20000, 256, deconv_w, 256, 256,
                                                      nullptr, 0, nullptr, 0, x1bf, tap);

  k_gnstat1<<<2500, 256, 0, stream>>>(x1bf, part);
  k_gnred1<<<16, 256, 0, stream>>>(part, gmv1);
  k_gnapply1<<<2048, 256, 0, stream>>>(x1bf, gmv1, gn1_g, gn1_b);

  k_conv3<<<dim3(100, 13), 256, 0, stream>>>(x1bf, wc3, c3);

  k_gnstat2<<<1920, 256, 0, stream>>>(c3, part);
  k_gnred2<<<16, 256, 0, stream>>>(part, gmv2);
  k_gnapply2<<<2048, 256, 0, stream>>>(c3, gmv2, gn2_g, gn2_b, out_x);
}

// Round 2
// 2175.473 us; speedup vs baseline: 1.1343x; 1.1343x over previous
//
#include <hip/hip_runtime.h>
#include <stdint.h>

typedef __attribute__((ext_vector_type(8))) short s16x8;
typedef __attribute__((ext_vector_type(4))) float f32x4;

static __device__ __forceinline__ unsigned short f2bf(float f) {
  unsigned u = __float_as_uint(f);
  u += 0x7FFFu + ((u >> 16) & 1u);
  return (unsigned short)(u >> 16);
}
static __device__ __forceinline__ float bf2f(unsigned short h) {
  return __uint_as_float(((unsigned)h) << 16);
}

// ---------------- weight prep ----------------
__global__ void k_wtct(const float* __restrict__ W, float* __restrict__ T) {
  int idx = blockIdx.x * 256 + threadIdx.x;        // 196608 = 768*256
  int k = idx >> 8, o = idx & 255;
  T[idx] = W[o * 768 + k];
}

__global__ void k_wc3(const float* __restrict__ W, unsigned short* __restrict__ T) {
  int idx = blockIdx.x * 256 + threadIdx.x;        // 1327104 = 27*192*256
  int tap = idx / 49152;
  int rem = idx - tap * 49152;
  int oc = rem >> 8, ic = rem & 255;
  T[idx] = f2bf(W[(oc * 256 + ic) * 27 + tap]);
}

// ---------------- restore + cam_x (output 2) ----------------
__global__ void k_restore(const float* __restrict__ cx, const int* __restrict__ ids,
                          const float* __restrict__ mtok, float* __restrict__ out) {
  int idx = blockIdx.x * 256 + threadIdx.x;        // 811008 = 6*768*176
  int p = idx % 176;
  int r = idx / 176;
  int ch = r % 768;
  int c = r / 768;
  int id = ids[c * 176 + p];
  out[idx] = (id < 44) ? cx[((size_t)(c * 44 + id)) * 768 + ch] : mtok[ch];
}

// ---------------- vf / feat: relu(camx @ W_tc^T + b) + embeds ----------------
__global__ __launch_bounds__(256) void k_vf(const float* __restrict__ camx, const float* __restrict__ WtT,
                                            const float* __restrict__ btc, const float* __restrict__ cemb,
                                            const float* __restrict__ lemb, float* __restrict__ feat) {
  __shared__ float sa[768];
  int blk = blockIdx.x;                            // c*176 + p
  int c = blk / 176, p = blk - c * 176;
  int t = threadIdx.x;
  for (int i = t; i < 768; i += 256) sa[i] = camx[((size_t)(c * 768 + i)) * 176 + p];
  __syncthreads();
  float acc = 0.f;
  for (int k = 0; k < 768; ++k) acc += sa[k] * WtT[k * 256 + t];
  feat[(size_t)blk * 256 + t] = fmaxf(acc + btc[t], 0.f) + cemb[c * 256 + t] + lemb[t];
}

// ---------------- generic bf16 MFMA GEMM ----------------
// mode 0: C[M,N] = act(A @ B + bias), split-B optional: cols < n1 from B (ldb=n1),
//         cols >= n1 from B2 (ldb = N-n1); bias/bias2 likewise.
// mode 1: deconv: N=2048, col -> (tap = col>>8, oc = col&255); B read as
//         deconv_w[oc][k][tap]; output scattered bf16 into x1[vox][256].
__global__ __launch_bounds__(256) void k_gemm(
    const float* __restrict__ A, int M, int lda,
    const float* __restrict__ B, int K, int N, int n1,
    const float* __restrict__ B2,
    const float* __restrict__ bias, const float* __restrict__ bias2, int relu,
    float* __restrict__ Cf, int ldc,
    unsigned short* __restrict__ Cscat, int mode) {
  __shared__ short sA[128 * 40];
  __shared__ short sB[64 * 40];
  const int t = threadIdx.x;
  const int l = t & 63, w = t >> 6;
  const int row0 = blockIdx.x * 128, n0 = blockIdx.y * 64;
  f32x4 acc[2][4] = {};
  const int rowA = t >> 1, halfA = t & 1;

  for (int kc = 0; kc < K; kc += 32) {
    __syncthreads();
    {  // stage A (convert f32 -> bf16)
      union { unsigned short s[8]; uint4 v; } p0, p1;
      int r = row0 + rowA;
      if (r < M) {
        const float* src = A + (size_t)r * lda + kc + halfA * 16;
        float4 f0 = ((const float4*)src)[0];
        float4 f1 = ((const float4*)src)[1];
        float4 f2 = ((const float4*)src)[2];
        float4 f3 = ((const float4*)src)[3];
        p0.s[0] = f2bf(f0.x); p0.s[1] = f2bf(f0.y); p0.s[2] = f2bf(f0.z); p0.s[3] = f2bf(f0.w);
        p0.s[4] = f2bf(f1.x); p0.s[5] = f2bf(f1.y); p0.s[6] = f2bf(f1.z); p0.s[7] = f2bf(f1.w);
        p1.s[0] = f2bf(f2.x); p1.s[1] = f2bf(f2.y); p1.s[2] = f2bf(f2.z); p1.s[3] = f2bf(f2.w);
        p1.s[4] = f2bf(f3.x); p1.s[5] = f2bf(f3.y); p1.s[6] = f2bf(f3.z); p1.s[7] = f2bf(f3.w);
      } else {
        p0.v = make_uint4(0u, 0u, 0u, 0u);
        p1.v = make_uint4(0u, 0u, 0u, 0u);
      }
      *(uint4*)&sA[rowA * 40 + halfA * 16] = p0.v;
      *(uint4*)&sA[rowA * 40 + halfA * 16 + 8] = p1.v;
    }
#pragma unroll
    for (int i = 0; i < 8; ++i) {  // stage B: [col][k] layout
      int e = t + i * 256;         // 2048 = 32k * 64n
      int kk = e >> 6, nn = e & 63;
      int n = n0 + nn;
      float v = 0.f;
      if (n < N) {
        if (mode == 1) v = B[(((size_t)(n & 255)) * 256 + kc + kk) * 8 + (n >> 8)];
        else if (n < n1) v = B[(size_t)(kc + kk) * n1 + n];
        else v = B2[(size_t)(kc + kk) * (N - n1) + (n - n1)];
      }
      sB[nn * 40 + kk] = (short)f2bf(v);
    }
    __syncthreads();
    s16x8 a0 = *(const s16x8*)&sA[(w * 32 + (l & 15)) * 40 + (l >> 4) * 8];
    s16x8 a1 = *(const s16x8*)&sA[(w * 32 + 16 + (l & 15)) * 40 + (l >> 4) * 8];
#pragma unroll
    for (int nb = 0; nb < 4; ++nb) {
      s16x8 b = *(const s16x8*)&sB[(nb * 16 + (l & 15)) * 40 + (l >> 4) * 8];
      acc[0][nb] = __builtin_amdgcn_mfma_f32_16x16x32_bf16(a0, b, acc[0][nb], 0, 0, 0);
      acc[1][nb] = __builtin_amdgcn_mfma_f32_16x16x32_bf16(a1, b, acc[1][nb], 0, 0, 0);
    }
  }
  // epilogue: C/D layout col = lane&15, row = (lane>>4)*4 + reg
#pragma unroll
  for (int m = 0; m < 2; ++m)
#pragma unroll
    for (int nb = 0; nb < 4; ++nb)
#pragma unroll
      for (int r = 0; r < 4; ++r) {
        int row = row0 + w * 32 + m * 16 + ((l >> 4) << 2) + r;
        int col = n0 + nb * 16 + (l & 15);
        if (row < M && col < N) {
          float v = acc[m][nb][r];
          if (bias) v += (col < n1) ? bias[col] : bias2[col - n1];
          if (relu) v = fmaxf(v, 0.f);
          if (mode == 1) {
            int tap = col >> 8, oc = col & 255;
            int z = row / 2500, rr = row - z * 2500;
            int hy = rr / 50, wx = rr - hy * 50;
            int t1 = tap >> 2, t2 = (tap >> 1) & 1, t3 = tap & 1;
            int od = 2 * wx + 1 - t1, oh = 2 * hy + 1 - t2, ow = 2 * z + 1 - t3;
            Cscat[((size_t)((od * 100 + oh) * 16 + ow)) * 256 + oc] = f2bf(v);
          } else {
            Cf[(size_t)row * ldc + col] = v;
          }
        }
      }
}

// ---------------- softmax + bilinear sampling + aggregate ----------------
// oa: fused [NQ][288] buffer: [0..192) = offsets, [192..288) = attn logits
__global__ __launch_bounds__(256) void k_sample(const float* __restrict__ oa,
                                                const float* __restrict__ val, float* __restrict__ agg) {
  __shared__ float sl[96], sw[96];
  int n = blockIdx.x, t = threadIdx.x;
  if (t < 96) sl[t] = oa[(size_t)n * 288 + 192 + t];
  __syncthreads();
  if (t < 8) {
    float mx = -1e30f;
    for (int j = 0; j < 12; ++j) mx = fmaxf(mx, sl[t * 12 + j]);
    float s = 0.f;
    for (int j = 0; j < 12; ++j) s += __expf(sl[t * 12 + j] - mx);
    float inv = 1.f / s;
    for (int j = 0; j < 12; ++j) sw[t * 12 + j] = __expf(sl[t * 12 + j] - mx) * inv;
  }
  __syncthreads();
  int h = t >> 5, d = t & 31;
  float xr = ((float)(n % 50) + 0.5f) * (22.0f / 50.0f) - 0.5f;
  float yr = ((float)((n / 50) % 50) + 0.5f) * (8.0f / 50.0f) - 0.5f;
  float acc = 0.f;
  const float* offn = oa + (size_t)n * 288 + h * 24;  // [h][c][p][2]
  const float* vbh = val + (size_t)h * 32 + d;
#pragma unroll
  for (int c = 0; c < 6; ++c)
#pragma unroll
    for (int p2 = 0; p2 < 2; ++p2) {
      float x = xr + offn[(c * 2 + p2) * 2];
      float y = yr + offn[(c * 2 + p2) * 2 + 1];
      float x0 = floorf(x), y0 = floorf(y);
      float wx = x - x0, wy = y - y0;
      int ix0 = min(max((int)x0, 0), 21), ix1 = min(max((int)x0 + 1, 0), 21);
      int iy0 = min(max((int)y0, 0), 7), iy1 = min(max((int)y0 + 1, 0), 7);
      const float* vb = vbh + (size_t)c * 176 * 256;
      float v00 = vb[(size_t)(iy0 * 22 + ix0) * 256];
      float v01 = vb[(size_t)(iy0 * 22 + ix1) * 256];
      float v10 = vb[(size_t)(iy1 * 22 + ix0) * 256];
      float v11 = vb[(size_t)(iy1 * 22 + ix1) * 256];
      float bil = (1.f - wx) * (1.f - wy) * v00 + wx * (1.f - wy) * v01 +
                  (1.f - wx) * wy * v10 + wx * wy * v11;
      acc += sw[h * 12 + c * 2 + p2] * bil;
    }
  agg[(size_t)n * 256 + t] = acc;
}

// ---------------- residual + LayerNorm(256), shuffle reduce ----------------
__global__ __launch_bounds__(256) void k_addln(float* __restrict__ q, const float* __restrict__ p,
                                               const float* __restrict__ g, const float* __restrict__ b) {
  __shared__ float red[8];
  int n = blockIdx.x, t = threadIdx.x;
  float x = q[(size_t)n * 256 + t] + p[(size_t)n * 256 + t];
  float s1 = x, s2 = x * x;
#pragma unroll
  for (int o = 32; o >= 1; o >>= 1) {
    s1 += __shfl_xor(s1, o, 64);
    s2 += __shfl_xor(s2, o, 64);
  }
  int w = t >> 6;
  if ((t & 63) == 0) { red[w * 2] = s1; red[w * 2 + 1] = s2; }
  __syncthreads();
  s1 = red[0] + red[2] + red[4] + red[6];
  s2 = red[1] + red[3] + red[5] + red[7];
  float mean = s1 * (1.0f / 256.0f);
  float var = s2 * (1.0f / 256.0f) - mean * mean;
  q[(size_t)n * 256 + t] = (x - mean) * rsqrtf(var + 1e-5f) * g[t] + b[t];
}

// ---------------- GroupNorm 1 (256 ch, 16 groups) over x1 [160000][256] bf16 ----------------
__global__ __launch_bounds__(256) void k_gnstat1(const unsigned short* __restrict__ X, float* __restrict__ part) {
  __shared__ float s1[256], s2[256];
  int b = blockIdx.x, t = threadIdx.x;   // 2500 blocks * 16384 elems
  unsigned base = (unsigned)b * 16384u + (unsigned)t;
  float a = 0.f, q = 0.f;
  for (int i = 0; i < 64; ++i) { float v = bf2f(X[base + (unsigned)i * 256u]); a += v; q += v * v; }
  s1[t] = a; s2[t] = q;
  __syncthreads();
  for (int s = 8; s > 0; s >>= 1) {
    if ((t & 15) < s) { s1[t] += s1[t + s]; s2[t] += s2[t + s]; }
    __syncthreads();
  }
  if ((t & 15) == 0) {
    part[(t >> 4) * 2500 + b] = s1[t];
    part[40000 + (t >> 4) * 2500 + b] = s2[t];
  }
}

__global__ __launch_bounds__(256) void k_gnred1(const float* __restrict__ part, float* __restrict__ gmv) {
  __shared__ float s1[256], s2[256];
  int g = blockIdx.x, t = threadIdx.x;   // 16 blocks
  float a = 0.f, q = 0.f;
  for (int i = t; i < 2500; i += 256) { a += part[g * 2500 + i]; q += part[40000 + g * 2500 + i]; }
  s1[t] = a; s2[t] = q;
  __syncthreads();
  for (int s = 128; s > 0; s >>= 1) {
    if (t < s) { s1[t] += s1[t + s]; s2[t] += s2[t + s]; }
    __syncthreads();
  }
  if (t == 0) {
    float m = s1[0] / 2560000.0f;
    float v = s2[0] / 2560000.0f - m * m;
    gmv[2 * g] = m; gmv[2 * g + 1] = rsqrtf(v + 1e-5f);
  }
}

__global__ __launch_bounds__(256) void k_gnapply1(unsigned short* __restrict__ X, const float* __restrict__ gmv,
                                                  const float* __restrict__ g, const float* __restrict__ b) {
  for (unsigned idx = blockIdx.x * 256 + threadIdx.x; idx < 40960000u; idx += gridDim.x * 256) {
    int oc = idx & 255, grp = oc >> 4;
    float v = bf2f(X[idx]);
    v = (v - gmv[grp * 2]) * gmv[grp * 2 + 1] * g[oc] + b[oc];
    X[idx] = f2bf(fmaxf(v, 0.f));
  }
}

// ---------------- conv3 3x3x3 (256->192) via tap-decomposed MFMA GEMM ----------------
// X: x1 normalized bf16 [vox=100*100*16][256]; Wp: [27][192][256] bf16; Y: [192][160000] bf16
// Conflict-free K-outer LDS layout + double-buffered weights (T14 async-stage).
__global__ __launch_bounds__(256) void k_conv3(const unsigned short* __restrict__ X,
                                               const unsigned short* __restrict__ Wp,
                                               unsigned short* __restrict__ Y) {
  __shared__ short sX[4][540][8];      // [kgrp][pos][8 bf16]  34.5 KB
  __shared__ short sW[2][4][192][8];   // dbuf [kgrp][oc][8]   24.6 KB
  const int od = blockIdx.x;           // 0..99
  const int oh0 = blockIdx.y * 8;      // 0..96
  const int t = threadIdx.x;
  const int l = t & 63, w = t >> 6;
  const int kg = l >> 4, lo = l & 15;
  f32x4 acc[8][3] = {};
  int cur = 0;

  for (int chunk = 0; chunk < 8; ++chunk) {
    const int ic0 = chunk * 32;
    __syncthreads();
    // stage slab: 540 pos x 4 kgrp uint4
#pragma unroll
    for (int i = 0; i < 9; ++i) {
      int e = t + i * 256;
      if (e < 2160) {
        int pos = e >> 2, kgs = e & 3;
        int sd = pos / 180, r2 = pos - sd * 180;
        int sh = r2 / 18, sw_ = r2 - sh * 18;
        int gd = od + sd - 1, gh = oh0 + sh - 1, gw = sw_ - 1;
        uint4 v = make_uint4(0u, 0u, 0u, 0u);
        if ((unsigned)gd < 100u && (unsigned)gh < 100u && (unsigned)gw < 16u)
          v = *(const uint4*)&X[((size_t)((gd * 100 + gh) * 16 + gw)) * 256 + ic0 + kgs * 8];
        *(uint4*)&sX[kgs][pos][0] = v;
      }
    }
    if (chunk == 0) {  // stage W(tap0, chunk0) into buf0
#pragma unroll
      for (int i = 0; i < 3; ++i) {
        int e = t + i * 256;
        int oc = e >> 2, kgs = e & 3;
        *(uint4*)&sW[0][kgs][oc][0] = *(const uint4*)&Wp[(size_t)oc * 256 + kgs * 8];
      }
    }
    __syncthreads();
    for (int tap = 0; tap < 27; ++tap) {
      // prefetch next weights (issue global loads early — T14)
      int ntap = tap + 1, nchunk = chunk;
      if (ntap == 27) { ntap = 0; nchunk = chunk + 1; }
      const bool pf = (nchunk < 8);
      uint4 wreg0, wreg1, wreg2;
      int oc0 = t >> 2, kg0 = t & 3;
      int oc1 = (t + 256) >> 2, kg1 = t & 3;
      int oc2 = (t + 512) >> 2, kg2 = t & 3;
      if (pf) {
        const unsigned short* wb = Wp + (size_t)ntap * 49152 + nchunk * 32;
        wreg0 = *(const uint4*)&wb[(size_t)oc0 * 256 + kg0 * 8];
        wreg1 = *(const uint4*)&wb[(size_t)oc1 * 256 + kg1 * 8];
        wreg2 = *(const uint4*)&wb[(size_t)oc2 * 256 + kg2 * 8];
      }
      const int t1 = tap / 9, tr = tap - t1 * 9, t2 = tr / 3, t3 = tr - t2 * 3;
      s16x8 a[8];
#pragma unroll
      for (int m = 0; m < 8; ++m) {
        int pos = (t1 * 10 + m + t2) * 18 + lo + t3;
        a[m] = *(const s16x8*)&sX[kg][pos][0];
      }
#pragma unroll
      for (int nb = 0; nb < 3; ++nb) {
        s16x8 b = *(const s16x8*)&sW[cur][kg][w * 48 + nb * 16 + lo][0];
#pragma unroll
        for (int m = 0; m < 8; ++m)
          acc[m][nb] = __builtin_amdgcn_mfma_f32_16x16x32_bf16(a[m], b, acc[m][nb], 0, 0, 0);
      }
      if (pf) {  // write-late into the other buffer
        *(uint4*)&sW[cur ^ 1][kg0][oc0][0] = wreg0;
        *(uint4*)&sW[cur ^ 1][kg1][oc1][0] = wreg1;
        *(uint4*)&sW[cur ^ 1][kg2][oc2][0] = wreg2;
      }
      cur ^= 1;
      __syncthreads();
    }
  }
  // epilogue: row = (l>>4)*4 + r within 16-voxel tile, col = oc
#pragma unroll
  for (int m = 0; m < 8; ++m) {
    int oh = oh0 + m;
    if (oh < 100) {
#pragma unroll
      for (int nb = 0; nb < 3; ++nb)
#pragma unroll
        for (int r = 0; r < 4; ++r) {
          int oc = w * 48 + nb * 16 + lo;
          int ow = (kg << 2) + r;
          Y[(size_t)oc * 160000 + (size_t)((od * 100 + oh) * 16) + ow] = f2bf(acc[m][nb][r]);
        }
    }
  }
}

// ---------------- GroupNorm 2 (192 ch, 16 groups) over [192][160000] bf16 ----------------
__global__ __launch_bounds__(256) void k_gnstat2(const unsigned short* __restrict__ X, float* __restrict__ part) {
  __shared__ float s1[256], s2[256];
  int b = blockIdx.x, t = threadIdx.x;   // 1920 blocks: ch = b/10, part p = b%10
  int ch = b / 10, pp = b - ch * 10;
  unsigned base = (unsigned)ch * 160000u + (unsigned)pp * 16000u;
  float a = 0.f, q = 0.f;
  for (int i = t; i < 16000; i += 256) { float v = bf2f(X[base + i]); a += v; q += v * v; }
  s1[t] = a; s2[t] = q;
  __syncthreads();
  for (int s = 128; s > 0; s >>= 1) {
    if (t < s) { s1[t] += s1[t + s]; s2[t] += s2[t + s]; }
    __syncthreads();
  }
  if (t == 0) { part[80000 + ch * 10 + pp] = s1[0]; part[81920 + ch * 10 + pp] = s2[0]; }
}

__global__ __launch_bounds__(256) void k_gnred2(const float* __restrict__ part, float* __restrict__ gmv) {
  __shared__ float s1[256], s2[256];
  int g = blockIdx.x, t = threadIdx.x;   // 16 blocks, 120 partials each (12 ch * 10)
  float a = (t < 120) ? part[80000 + g * 120 + t] : 0.f;
  float q = (t < 120) ? part[81920 + g * 120 + t] : 0.f;
  s1[t] = a; s2[t] = q;
  __syncthreads();
  for (int s = 128; s > 0; s >>= 1) {
    if (t < s) { s1[t] += s1[t + s]; s2[t] += s2[t + s]; }
    __syncthreads();
  }
  if (t == 0) {
    float m = s1[0] / 1920000.0f;
    float v = s2[0] / 1920000.0f - m * m;
    gmv[2 * g] = m; gmv[2 * g + 1] = rsqrtf(v + 1e-5f);
  }
}

__global__ __launch_bounds__(256) void k_gnapply2(const unsigned short* __restrict__ X, const float* __restrict__ gmv,
                                                  const float* __restrict__ g, const float* __restrict__ b,
                                                  float* __restrict__ out) {
  for (unsigned idx = blockIdx.x * 256 + threadIdx.x; idx < 30720000u; idx += gridDim.x * 256) {
    unsigned oc = idx / 160000u;
    unsigned grp = oc / 12u;
    float v = bf2f(X[idx]);
    v = (v - gmv[grp * 2]) * gmv[grp * 2 + 1] * g[oc] + b[oc];
    out[idx] = fmaxf(v, 0.f);
  }
}

// ---------------- host ----------------
static inline dim3 gemm_grid(int M, int N) { return dim3((M + 127) / 128, (N + 63) / 64); }

extern "C" void kernel_launch(void* const* d_in, const int* in_sizes, int n_in,
                              void* d_out, int out_size, void* d_ws, size_t ws_size,
                              hipStream_t stream) {
  const float* camera_x = (const float*)d_in[0];
  const int* ids = (const int*)d_in[1];
  const float* mask_tok = (const float*)d_in[4];
  const float* vol_emb = (const float*)d_in[5];
  const float* W_tc = (const float*)d_in[6];
  const float* b_tc = (const float*)d_in[7];
  const float* cams_emb = (const float*)d_in[8];
  const float* lvl_emb = (const float*)d_in[9];
  const float* W_off = (const float*)d_in[10];
  const float* b_off = (const float*)d_in[11];
  const float* W_att = (const float*)d_in[12];
  const float* b_att = (const float*)d_in[13];
  const float* W_val = (const float*)d_in[14];
  const float* b_val = (const float*)d_in[15];
  const float* W_out = (const float*)d_in[16];
  const float* b_out = (const float*)d_in[17];
  const float* ln1_g = (const float*)d_in[18];
  const float* ln1_b = (const float*)d_in[19];
  const float* W_ff1 = (const float*)d_in[20];
  const float* b_ff1 = (const float*)d_in[21];
  const float* W_ff2 = (const float*)d_in[22];
  const float* b_ff2 = (const float*)d_in[23];
  const float* ln2_g = (const float*)d_in[24];
  const float* ln2_b = (const float*)d_in[25];
  const float* deconv_w = (const float*)d_in[26];
  const float* gn1_g = (const float*)d_in[27];
  const float* gn1_b = (const float*)d_in[28];
  const float* conv3_w = (const float*)d_in[29];
  const float* gn2_g = (const float*)d_in[30];
  const float* gn2_b = (const float*)d_in[31];

  char* ws = (char*)d_ws;
  float* q = (float*)(ws + 0);
  float* feat = (float*)(ws + 81920000);
  float* val = (float*)(ws + 83001344);
  float* oa = (float*)(ws + 84082688);                       // [20000][288]
  float* agg = (float*)(ws + 84082688 + 23040000);
  float* proj = (float*)(ws + 84082688 + 43520000);
  float* ffh = (float*)(ws + 84082688 + 64000000);
  unsigned short* x1bf = (unsigned short*)(ws + 84082688);   // aliases decoder scratch (dead)
  unsigned short* c3 = (unsigned short*)(ws + 0);            // aliases q (dead after deconv)
  float* wtcT = (float*)(ws + 189042688);
  unsigned short* wc3 = (unsigned short*)(ws + 189829120);
  float* part = (float*)(ws + 192483328);
  float* gmv1 = (float*)(ws + 192818688);
  float* gmv2 = (float*)(ws + 192818816);

  float* out_x = (float*)d_out;
  float* out_camx = out_x + 30720000;

  k_wtct<<<768, 256, 0, stream>>>(W_tc, wtcT);
  k_wc3<<<5184, 256, 0, stream>>>(conv3_w, wc3);
  k_restore<<<3168, 256, 0, stream>>>(camera_x, ids, mask_tok, out_camx);
  k_vf<<<1056, 256, 0, stream>>>(out_camx, wtcT, b_tc, cams_emb, lvl_emb, feat);
  hipMemcpyAsync(q, vol_emb, (size_t)20000 * 256 * 4, hipMemcpyDeviceToDevice, stream);

  for (int lyr = 0; lyr < 3; ++lyr) {
    k_gemm<<<gemm_grid(1056, 256), 256, 0, stream>>>(feat, 1056, 256, W_val + lyr * 65536, 256, 256, 256,
                                                     nullptr, b_val + lyr * 256, nullptr, 0, val, 256, nullptr, 0);
    // fused off(192) + att(96) projection -> oa[20000][288]
    k_gemm<<<gemm_grid(20000, 288), 256, 0, stream>>>(q, 20000, 256, W_off + lyr * 49152, 256, 288, 192,
                                                      W_att + lyr * 24576, b_off + lyr * 192, b_att + lyr * 96, 0,
                                                      oa, 288, nullptr, 0);
    k_sample<<<20000, 256, 0, stream>>>(oa, val, agg);
    k_gemm<<<gemm_grid(20000, 256), 256, 0, stream>>>(agg, 20000, 256, W_out + lyr * 65536, 256, 256, 256,
                                                      nullptr, b_out + lyr * 256, nullptr, 0, proj, 256, nullptr, 0);
    k_addln<<<20000, 256, 0, stream>>>(q, proj, ln1_g + lyr * 256, ln1_b + lyr * 256);
    k_gemm<<<gemm_grid(20000, 512), 256, 0, stream>>>(q, 20000, 256, W_ff1 + lyr * 131072, 256, 512, 512,
                                                      nullptr, b_ff1 + lyr * 512, nullptr, 1, ffh, 512, nullptr, 0);
    k_gemm<<<gemm_grid(20000, 256), 256, 0, stream>>>(ffh, 20000, 512, W_ff2 + lyr * 131072, 512, 256, 256,
                                                      nullptr, b_ff2 + lyr * 256, nullptr, 0, proj, 256, nullptr, 0);
    k_addln<<<20000, 256, 0, stream>>>(q, proj, ln2_g + lyr * 256, ln2_b + lyr * 256);
  }

  // deconv: all 8 taps in one GEMM (N = 8*256 = 2048), scattered bf16 output
  k_gemm<<<gemm_grid(20000, 2048), 256, 0, stream>>>(q, 20000, 256, deconv_w, 256, 2048, 2048,
                                                     nullptr, nullptr, nullptr, 0, nullptr, 0, x1bf, 1);

  k_gnstat1<<<2500, 256, 0, stream>>>(x1bf, part);
  k_gnred1<<<16, 256, 0, stream>>>(part, gmv1);
  k_gnapply1<<<2048, 256, 0, stream>>>(x1bf, gmv1, gn1_g, gn1_b);

  k_conv3<<<dim3(100, 13), 256, 0, stream>>>(x1bf, wc3, c3);

  k_gnstat2<<<1920, 256, 0, stream>>>(c3, part);
  k_gnred2<<<16, 256, 0, stream>>>(part, gmv2);
  k_gnapply2<<<2048, 256, 0, stream>>>(c3, gmv2, gn2_g, gn2_b, out_x);
}